// Round 5
// baseline (665.240 us; speedup 1.0000x reference)
//
#include <hip/hip_runtime.h>

#define NN 100000
#define NE 1600000
#define KB 782      // coarse buckets: ceil(100000/128)
#define BSH 7       // bucket = dst >> 7; 128 nodes per bucket
#define MAXB 4096   // max edges per bucket (mean 2046, sigma ~45 -> 4096 is unreachable)

// Workspace layout in 4-byte units (total 24,048,128 uints = 96.2 MB):
#define OFF_CB    0            // 1024: coarse hist -> exclusive offsets (cb[KB] = NE)
#define OFF_CC    1024         // 1024: partition cursors
#define OFF_STAGE 2048         // NE uints: packed (dstLow<<17)|src, bucket-ordered
#define OFF_XB    1602048      // x bf16 [100096,128]
#define OFF_MEANB 8008192      // mean bf16 [100096,128]; meanp fp32 [100096,64] aliases
#define OFF_HB    14414336     // h bf16 [100096,128]
#define OFF_PB    20820480     // pl bf16 [100096,64]
#define OFF_W1LP  24023552     // packed weights bf16
#define OFF_W1RP  (24023552 + 8192)
#define OFF_W2LP  (24023552 + 16384)
#define OFF_W2RP  (24023552 + 20480)

typedef __bf16 bf16x8 __attribute__((ext_vector_type(8)));
typedef float f32x4 __attribute__((ext_vector_type(4)));

static __device__ __forceinline__ ushort f2bf(float f) {
    unsigned u = __float_as_uint(f);
    return (ushort)((u + 0x7fffu + ((u >> 16) & 1u)) >> 16);
}
static __device__ __forceinline__ float bflo(unsigned u) { return __uint_as_float(u << 16); }
static __device__ __forceinline__ float bfhi(unsigned u) { return __uint_as_float(u & 0xffff0000u); }

// ---------------------------------------------------------------------------
// x (fp32) -> xb (bf16). One float4 per thread.
// ---------------------------------------------------------------------------
__global__ void cvt_kernel(const float* __restrict__ x, ushort* __restrict__ xb) {
    int i = blockIdx.x * 256 + threadIdx.x;  // covers NN*128/4 = 3.2M
    float4 v = ((const float4*)x)[i];
    uint2 o;
    o.x = (unsigned)f2bf(v.x) | ((unsigned)f2bf(v.y) << 16);
    o.y = (unsigned)f2bf(v.z) | ((unsigned)f2bf(v.w) << 16);
    ((uint2*)xb)[i] = o;
}

// ---------------------------------------------------------------------------
// Pack all 4 weight matrices fp32 -> bf16 MFMA B-frag layout.
// ---------------------------------------------------------------------------
__global__ void pack_kernel(const float* __restrict__ W1l, const float* __restrict__ W1r,
                            const float* __restrict__ W2l, const float* __restrict__ W2r,
                            ushort* __restrict__ w1lp, ushort* __restrict__ w1rp,
                            ushort* __restrict__ w2lp, ushort* __restrict__ w2rp) {
    int blk = blockIdx.x;
    const float* W;
    ushort* out;
    int N, frag0;
    if (blk < 8)       { W = W1l; out = w1lp; N = 128; frag0 = blk * 4; }
    else if (blk < 16) { W = W1r; out = w1rp; N = 128; frag0 = (blk - 8) * 4; }
    else if (blk < 20) { W = W2l; out = w2lp; N = 64;  frag0 = (blk - 16) * 4; }
    else               { W = W2r; out = w2rp; N = 64;  frag0 = (blk - 20) * 4; }
    int lane = threadIdx.x & 63;
    int frag = frag0 + (threadIdx.x >> 6);
    int NT = N >> 4;
    int ktile = frag / NT, ntile = frag - ktile * NT;
    int k = ktile * 32 + (lane >> 4) * 8;
    int n = ntile * 16 + (lane & 15);
    ushort tmp[8];
#pragma unroll
    for (int j = 0; j < 8; ++j) tmp[j] = f2bf(W[(k + j) * N + n]);
    uint4 o;
    o.x = (unsigned)tmp[0] | ((unsigned)tmp[1] << 16);
    o.y = (unsigned)tmp[2] | ((unsigned)tmp[3] << 16);
    o.z = (unsigned)tmp[4] | ((unsigned)tmp[5] << 16);
    o.w = (unsigned)tmp[6] | ((unsigned)tmp[7] << 16);
    *(uint4*)&out[(frag * 64 + lane) * 8] = o;
}

// ---------------------------------------------------------------------------
// Coarse histogram: counts per 128-node dst block, LDS-privatized.
// ---------------------------------------------------------------------------
__global__ __launch_bounds__(256) void chist_kernel(const int* __restrict__ dst,
                                                    int* __restrict__ cb) {
    __shared__ int h[KB];
    int t = threadIdx.x;
    for (int i = t; i < KB; i += 256) h[i] = 0;
    __syncthreads();
    for (int e = blockIdx.x * 256 + t; e < NE; e += gridDim.x * 256)
        atomicAdd(&h[dst[e] >> BSH], 1);
    __syncthreads();
    for (int i = t; i < KB; i += 256)
        if (h[i]) atomicAdd(&cb[i], h[i]);
}

// ---------------------------------------------------------------------------
// Scan KB counts -> exclusive offsets in cb (cb[KB]=NE) and cursor copy in cc.
// ---------------------------------------------------------------------------
__global__ __launch_bounds__(1024) void cscan_kernel(int* __restrict__ cb,
                                                     int* __restrict__ cc) {
    __shared__ int s[1024];
    int t = threadIdx.x;
    s[t] = (t < KB) ? cb[t] : 0;
    __syncthreads();
    for (int off = 1; off < 1024; off <<= 1) {
        int v = (t >= off) ? s[t - off] : 0;
        __syncthreads();
        s[t] += v;
        __syncthreads();
    }
    if (t < KB) {
        int excl = (t == 0) ? 0 : s[t - 1];
        cb[t] = excl;
        cc[t] = excl;
    }
    if (t == KB - 1) cb[KB] = s[t];
}

// ---------------------------------------------------------------------------
// Coarse partition: stage[pos] = (dst&127)<<17 | src, bucket-ordered.
// Only 782 active write cursors -> lines fill completely -> ~6.4MB writeback.
// ---------------------------------------------------------------------------
__global__ __launch_bounds__(256) void cpart_kernel(const int* __restrict__ src,
                                                    const int* __restrict__ dst,
                                                    int* __restrict__ cc,
                                                    unsigned* __restrict__ stage) {
    int e = blockIdx.x * 256 + threadIdx.x;
    if (e >= NE) return;
    int s = src[e], d = dst[e];
    int pos = atomicAdd(&cc[d >> BSH], 1);
    stage[pos] = ((unsigned)(d & 127) << 17) | (unsigned)s;
}

// ---------------------------------------------------------------------------
// Fused aggregation, layer 1: one block per coarse bucket. Build local CSR in
// LDS (hist/scan/scatter), then half-wave per node gathers bf16 x rows
// (uint2/lane, 256B/edge) and writes mean bf16. No global CSR at all.
// ---------------------------------------------------------------------------
__global__ __launch_bounds__(256) void agg1f_kernel(const unsigned* __restrict__ stage,
                                                    const int* __restrict__ cb,
                                                    const ushort* __restrict__ xb,
                                                    ushort* __restrict__ meanb) {
    __shared__ unsigned raw[MAXB];
    __shared__ unsigned ssrc[MAXB];
    __shared__ int sc[128];
    __shared__ int loff[129];
    __shared__ int lcur[128];
    int t = threadIdx.x;
    int b = blockIdx.x;
    int estart = cb[b], eend = cb[b + 1];
    int cnt = eend - estart;

    for (int i = t; i < cnt; i += 256) raw[i] = stage[estart + i];
    if (t < 128) lcur[t] = 0;
    __syncthreads();
    for (int i = t; i < cnt; i += 256) atomicAdd(&lcur[raw[i] >> 17], 1);
    __syncthreads();
    if (t < 128) sc[t] = lcur[t];
    __syncthreads();
    for (int off = 1; off < 128; off <<= 1) {
        int v = (t < 128 && t >= off) ? sc[t - off] : 0;
        __syncthreads();
        if (t < 128) sc[t] += v;
        __syncthreads();
    }
    if (t < 128) {
        int excl = (t == 0) ? 0 : sc[t - 1];
        loff[t] = excl;
        lcur[t] = excl;
    }
    if (t == 127) loff[128] = sc[127];
    __syncthreads();
    for (int i = t; i < cnt; i += 256) {
        unsigned v = raw[i];
        int p = atomicAdd(&lcur[v >> 17], 1);
        ssrc[p] = v & 0x1FFFFu;
    }
    __syncthreads();

    int hw = t >> 5, l5 = t & 31;
    int node0 = b << BSH;
    int nmax = min(128, NN - node0);
    const unsigned* xbu = (const unsigned*)xb;
    int co = 2 * l5;
    for (int nl = hw; nl < nmax; nl += 8) {
        int s0 = loff[nl], s1 = loff[nl + 1];
        float a0 = 0.f, a1 = 0.f, a2 = 0.f, a3 = 0.f;
        int e = s0;
        for (; e + 4 <= s1; e += 4) {
            int q0 = ssrc[e + 0] * 64;
            int q1 = ssrc[e + 1] * 64;
            int q2 = ssrc[e + 2] * 64;
            int q3 = ssrc[e + 3] * 64;
            uint2 u0 = *(const uint2*)&xbu[q0 + co];
            uint2 u1 = *(const uint2*)&xbu[q1 + co];
            uint2 u2 = *(const uint2*)&xbu[q2 + co];
            uint2 u3 = *(const uint2*)&xbu[q3 + co];
            a0 += bflo(u0.x) + bflo(u1.x) + bflo(u2.x) + bflo(u3.x);
            a1 += bfhi(u0.x) + bfhi(u1.x) + bfhi(u2.x) + bfhi(u3.x);
            a2 += bflo(u0.y) + bflo(u1.y) + bflo(u2.y) + bflo(u3.y);
            a3 += bfhi(u0.y) + bfhi(u1.y) + bfhi(u2.y) + bfhi(u3.y);
        }
        for (; e < s1; ++e) {
            uint2 u = *(const uint2*)&xbu[ssrc[e] * 64 + co];
            a0 += bflo(u.x); a1 += bfhi(u.x); a2 += bflo(u.y); a3 += bfhi(u.y);
        }
        float inv = 1.0f / fmaxf((float)(s1 - s0), 1.0f);
        uint2 o;
        o.x = (unsigned)f2bf(a0 * inv) | ((unsigned)f2bf(a1 * inv) << 16);
        o.y = (unsigned)f2bf(a2 * inv) | ((unsigned)f2bf(a3 * inv) << 16);
        *(uint2*)&((unsigned*)meanb)[(node0 + nl) * 64 + co] = o;
    }
}

// ---------------------------------------------------------------------------
// Fused aggregation, layer 2: same local-CSR structure; gathers bf16 pl rows
// (uint/lane, 128B/edge, 12.8MB table), writes meanp fp32.
// ---------------------------------------------------------------------------
__global__ __launch_bounds__(256) void agg2f_kernel(const unsigned* __restrict__ stage,
                                                    const int* __restrict__ cb,
                                                    const ushort* __restrict__ pb,
                                                    float* __restrict__ meanp) {
    __shared__ unsigned raw[MAXB];
    __shared__ unsigned ssrc[MAXB];
    __shared__ int sc[128];
    __shared__ int loff[129];
    __shared__ int lcur[128];
    int t = threadIdx.x;
    int b = blockIdx.x;
    int estart = cb[b], eend = cb[b + 1];
    int cnt = eend - estart;

    for (int i = t; i < cnt; i += 256) raw[i] = stage[estart + i];
    if (t < 128) lcur[t] = 0;
    __syncthreads();
    for (int i = t; i < cnt; i += 256) atomicAdd(&lcur[raw[i] >> 17], 1);
    __syncthreads();
    if (t < 128) sc[t] = lcur[t];
    __syncthreads();
    for (int off = 1; off < 128; off <<= 1) {
        int v = (t < 128 && t >= off) ? sc[t - off] : 0;
        __syncthreads();
        if (t < 128) sc[t] += v;
        __syncthreads();
    }
    if (t < 128) {
        int excl = (t == 0) ? 0 : sc[t - 1];
        loff[t] = excl;
        lcur[t] = excl;
    }
    if (t == 127) loff[128] = sc[127];
    __syncthreads();
    for (int i = t; i < cnt; i += 256) {
        unsigned v = raw[i];
        int p = atomicAdd(&lcur[v >> 17], 1);
        ssrc[p] = v & 0x1FFFFu;
    }
    __syncthreads();

    int hw = t >> 5, l5 = t & 31;
    int node0 = b << BSH;
    int nmax = min(128, NN - node0);
    const unsigned* pbu = (const unsigned*)pb;
    for (int nl = hw; nl < nmax; nl += 8) {
        int s0 = loff[nl], s1 = loff[nl + 1];
        float a0 = 0.f, a1 = 0.f;
        int e = s0;
        for (; e + 4 <= s1; e += 4) {
            unsigned u0 = pbu[ssrc[e + 0] * 32 + l5];
            unsigned u1 = pbu[ssrc[e + 1] * 32 + l5];
            unsigned u2 = pbu[ssrc[e + 2] * 32 + l5];
            unsigned u3 = pbu[ssrc[e + 3] * 32 + l5];
            a0 += bflo(u0) + bflo(u1) + bflo(u2) + bflo(u3);
            a1 += bfhi(u0) + bfhi(u1) + bfhi(u2) + bfhi(u3);
        }
        for (; e < s1; ++e) {
            unsigned u = pbu[ssrc[e] * 32 + l5];
            a0 += bflo(u); a1 += bfhi(u);
        }
        float inv = 1.0f / fmaxf((float)(s1 - s0), 1.0f);
        float2 o = {a0 * inv, a1 * inv};
        *(float2*)&meanp[(node0 + nl) * 64 + 2 * l5] = o;
    }
}

// ---------------------------------------------------------------------------
// GEMM1 (MFMA): h = relu(mean@W1l + x@W1r + b1); hb = bf16(h); pb = bf16(h@W2l).
// ---------------------------------------------------------------------------
__global__ __launch_bounds__(256) void gemm1_kernel(const ushort* __restrict__ meanb,
                                                    const ushort* __restrict__ xb,
                                                    const ushort* __restrict__ w1lp,
                                                    const ushort* __restrict__ w1rp,
                                                    const float* __restrict__ b1,
                                                    const ushort* __restrict__ w2lp,
                                                    ushort* __restrict__ hb,
                                                    ushort* __restrict__ pb) {
    __shared__ ushort As[64 * 136];
    int t = threadIdx.x;
    int node0 = blockIdx.x * 64;
    int w = t >> 6, l = t & 63;
    int lrow = w * 16 + (l & 15);
    int lkq = (l >> 4) * 8;
    int cq = l & 15, rq = (l >> 4) * 4;

    f32x4 acc[8];
#pragma unroll
    for (int i = 0; i < 8; ++i) acc[i] = (f32x4){0.f, 0.f, 0.f, 0.f};

    {
        const uint4* g = (const uint4*)(meanb + (size_t)node0 * 128);
#pragma unroll
        for (int i = 0; i < 4; ++i) {
            int chunk = t + 256 * i;
            *(uint4*)&As[(chunk >> 4) * 136 + (chunk & 15) * 8] = g[chunk];
        }
    }
    __syncthreads();
#pragma unroll
    for (int kt = 0; kt < 4; ++kt) {
        bf16x8 a = *(const bf16x8*)&As[lrow * 136 + kt * 32 + lkq];
        const bf16x8* bp = (const bf16x8*)w1lp + (kt * 8) * 64 + l;
#pragma unroll
        for (int nt = 0; nt < 8; ++nt)
            acc[nt] = __builtin_amdgcn_mfma_f32_16x16x32_bf16(a, bp[nt * 64], acc[nt], 0, 0, 0);
    }
    __syncthreads();

    {
        const uint4* g = (const uint4*)(xb + (size_t)node0 * 128);
#pragma unroll
        for (int i = 0; i < 4; ++i) {
            int chunk = t + 256 * i;
            *(uint4*)&As[(chunk >> 4) * 136 + (chunk & 15) * 8] = g[chunk];
        }
    }
    __syncthreads();
#pragma unroll
    for (int kt = 0; kt < 4; ++kt) {
        bf16x8 a = *(const bf16x8*)&As[lrow * 136 + kt * 32 + lkq];
        const bf16x8* bp = (const bf16x8*)w1rp + (kt * 8) * 64 + l;
#pragma unroll
        for (int nt = 0; nt < 8; ++nt)
            acc[nt] = __builtin_amdgcn_mfma_f32_16x16x32_bf16(a, bp[nt * 64], acc[nt], 0, 0, 0);
    }
    __syncthreads();

#pragma unroll
    for (int nt = 0; nt < 8; ++nt) {
        int n = nt * 16 + cq;
        float bias = b1[n];
#pragma unroll
        for (int r = 0; r < 4; ++r) {
            float hv = fmaxf(acc[nt][r] + bias, 0.0f);
            As[(w * 16 + rq + r) * 136 + n] = f2bf(hv);
        }
    }
    __syncthreads();

    {
        uint4* g = (uint4*)(hb + (size_t)node0 * 128);
#pragma unroll
        for (int i = 0; i < 4; ++i) {
            int chunk = t + 256 * i;
            if (node0 + (chunk >> 4) < NN)
                g[chunk] = *(const uint4*)&As[(chunk >> 4) * 136 + (chunk & 15) * 8];
        }
    }

    f32x4 acc2[4];
#pragma unroll
    for (int i = 0; i < 4; ++i) acc2[i] = (f32x4){0.f, 0.f, 0.f, 0.f};
#pragma unroll
    for (int kt = 0; kt < 4; ++kt) {
        bf16x8 a = *(const bf16x8*)&As[lrow * 136 + kt * 32 + lkq];
        const bf16x8* bp = (const bf16x8*)w2lp + (kt * 4) * 64 + l;
#pragma unroll
        for (int nt = 0; nt < 4; ++nt)
            acc2[nt] = __builtin_amdgcn_mfma_f32_16x16x32_bf16(a, bp[nt * 64], acc2[nt], 0, 0, 0);
    }
    __syncthreads();

#pragma unroll
    for (int nt = 0; nt < 4; ++nt)
#pragma unroll
        for (int r = 0; r < 4; ++r)
            As[(w * 16 + rq + r) * 136 + nt * 16 + cq] = f2bf(acc2[nt][r]);
    __syncthreads();
    {
        uint4* g = (uint4*)(pb + (size_t)node0 * 64);
#pragma unroll
        for (int i = 0; i < 2; ++i) {
            int chunk = t + 256 * i;
            if (node0 + (chunk >> 3) < NN)
                g[chunk] = *(const uint4*)&As[(chunk >> 3) * 136 + (chunk & 7) * 8];
        }
    }
}

// ---------------------------------------------------------------------------
// GEMM2 (MFMA): out = meanp + hb@W2r + b2.
// ---------------------------------------------------------------------------
__global__ __launch_bounds__(256) void gemm2_kernel(const float* __restrict__ meanp,
                                                    const ushort* __restrict__ hb,
                                                    const ushort* __restrict__ w2rp,
                                                    const float* __restrict__ b2,
                                                    float* __restrict__ out) {
    __shared__ ushort As[64 * 136];
    int t = threadIdx.x;
    int node0 = blockIdx.x * 64;
    int w = t >> 6, l = t & 63;
    int lrow = w * 16 + (l & 15);
    int lkq = (l >> 4) * 8;
    int cq = l & 15, rq = (l >> 4) * 4;

    {
        const uint4* g = (const uint4*)(hb + (size_t)node0 * 128);
#pragma unroll
        for (int i = 0; i < 4; ++i) {
            int chunk = t + 256 * i;
            *(uint4*)&As[(chunk >> 4) * 136 + (chunk & 15) * 8] = g[chunk];
        }
    }
    __syncthreads();

    f32x4 acc[4];
#pragma unroll
    for (int i = 0; i < 4; ++i) acc[i] = (f32x4){0.f, 0.f, 0.f, 0.f};
#pragma unroll
    for (int kt = 0; kt < 4; ++kt) {
        bf16x8 a = *(const bf16x8*)&As[lrow * 136 + kt * 32 + lkq];
        const bf16x8* bp = (const bf16x8*)w2rp + (kt * 4) * 64 + l;
#pragma unroll
        for (int nt = 0; nt < 4; ++nt)
            acc[nt] = __builtin_amdgcn_mfma_f32_16x16x32_bf16(a, bp[nt * 64], acc[nt], 0, 0, 0);
    }

#pragma unroll
    for (int nt = 0; nt < 4; ++nt) {
        int n = nt * 16 + cq;
        float bias = b2[n];
#pragma unroll
        for (int r = 0; r < 4; ++r) {
            int row = node0 + w * 16 + rq + r;
            if (row < NN)
                out[(size_t)row * 64 + n] = acc[nt][r] + bias + meanp[(size_t)row * 64 + n];
        }
    }
}

extern "C" void kernel_launch(void* const* d_in, const int* in_sizes, int n_in,
                              void* d_out, int out_size, void* d_ws, size_t ws_size,
                              hipStream_t stream) {
    const float* x   = (const float*)d_in[0];
    const int*   ei  = (const int*)d_in[1];
    const float* W1l = (const float*)d_in[2];
    const float* W1r = (const float*)d_in[3];
    const float* b1  = (const float*)d_in[4];
    const float* W2l = (const float*)d_in[5];
    const float* W2r = (const float*)d_in[6];
    const float* b2  = (const float*)d_in[7];

    const int* src = ei;
    const int* dst = ei + NE;

    int*      ws_i  = (int*)d_ws;
    int*      cb    = ws_i + OFF_CB;
    int*      cc    = ws_i + OFF_CC;
    unsigned* stage = (unsigned*)(ws_i + OFF_STAGE);
    ushort*   xb    = (ushort*)(ws_i + OFF_XB);
    ushort*   meanb = (ushort*)(ws_i + OFF_MEANB);
    float*    meanp = (float*)(ws_i + OFF_MEANB);  // aliases meanb (disjoint lifetime)
    ushort*   hb    = (ushort*)(ws_i + OFF_HB);
    ushort*   pb    = (ushort*)(ws_i + OFF_PB);
    ushort*   w1lp  = (ushort*)(ws_i + OFF_W1LP);
    ushort*   w1rp  = (ushort*)(ws_i + OFF_W1RP);
    ushort*   w2lp  = (ushort*)(ws_i + OFF_W2LP);
    ushort*   w2rp  = (ushort*)(ws_i + OFF_W2RP);

    // Prep: zero coarse hist, convert x, pack weights, build coarse partition.
    hipMemsetAsync(cb, 0, 1024 * sizeof(int), stream);
    cvt_kernel<<<12500, 256, 0, stream>>>(x, xb);
    pack_kernel<<<24, 256, 0, stream>>>(W1l, W1r, W2l, W2r, w1lp, w1rp, w2lp, w2rp);
    chist_kernel<<<256, 256, 0, stream>>>(dst, cb);
    cscan_kernel<<<1, 1024, 0, stream>>>(cb, cc);
    cpart_kernel<<<(NE + 255) / 256, 256, 0, stream>>>(src, dst, cc, stage);

    // Layer 1
    agg1f_kernel<<<KB, 256, 0, stream>>>(stage, cb, xb, meanb);
    gemm1_kernel<<<(NN + 63) / 64, 256, 0, stream>>>(meanb, xb, w1lp, w1rp, b1, w2lp, hb, pb);

    // Layer 2 (aggregation commuted past W2l)
    agg2f_kernel<<<KB, 256, 0, stream>>>(stage, cb, pb, meanp);
    gemm2_kernel<<<(NN + 63) / 64, 256, 0, stream>>>(meanp, hb, w2rp, b2, (float*)d_out);
}

// Round 6
// 327.599 us; speedup vs baseline: 2.0307x; 2.0307x over previous
//
#include <hip/hip_runtime.h>

#define NN 100000
#define NE 1600000
#define KB 782      // coarse buckets: ceil(100000/128)
#define BSH 7       // bucket = dst >> 7; 128 nodes per bucket
#define MAXB 4096   // max edges per bucket (mean 2046, tight binomial tail)
#define PBLK 100    // cpart blocks; NE/PBLK = 16000 edges per block

// Workspace layout in 4-byte units (total 24,048,128 uints = 96.2 MB):
#define OFF_CB    0            // 1024: coarse hist -> exclusive offsets (cb[KB] = NE)
#define OFF_CC    1024         // 1024: partition cursors
#define OFF_STAGE 2048         // NE uints: packed (dstLow<<17)|src, bucket-ordered
#define OFF_XB    1602048      // x bf16 [100096,128]
#define OFF_MEANB 8008192      // mean bf16 [100096,128]; meanp fp32 [100096,64] aliases
#define OFF_HB    14414336     // h bf16 [100096,128]
#define OFF_PB    20820480     // pl bf16 [100096,64]
#define OFF_W1LP  24023552     // packed weights bf16
#define OFF_W1RP  (24023552 + 8192)
#define OFF_W2LP  (24023552 + 16384)
#define OFF_W2RP  (24023552 + 20480)

typedef __bf16 bf16x8 __attribute__((ext_vector_type(8)));
typedef float f32x4 __attribute__((ext_vector_type(4)));

static __device__ __forceinline__ ushort f2bf(float f) {
    unsigned u = __float_as_uint(f);
    return (ushort)((u + 0x7fffu + ((u >> 16) & 1u)) >> 16);
}
static __device__ __forceinline__ float bflo(unsigned u) { return __uint_as_float(u << 16); }
static __device__ __forceinline__ float bfhi(unsigned u) { return __uint_as_float(u & 0xffff0000u); }

// ---------------------------------------------------------------------------
// x (fp32) -> xb (bf16). One float4 per thread.
// ---------------------------------------------------------------------------
__global__ void cvt_kernel(const float* __restrict__ x, ushort* __restrict__ xb) {
    int i = blockIdx.x * 256 + threadIdx.x;  // covers NN*128/4 = 3.2M
    float4 v = ((const float4*)x)[i];
    uint2 o;
    o.x = (unsigned)f2bf(v.x) | ((unsigned)f2bf(v.y) << 16);
    o.y = (unsigned)f2bf(v.z) | ((unsigned)f2bf(v.w) << 16);
    ((uint2*)xb)[i] = o;
}

// ---------------------------------------------------------------------------
// Pack all 4 weight matrices fp32 -> bf16 MFMA B-frag layout.
// ---------------------------------------------------------------------------
__global__ void pack_kernel(const float* __restrict__ W1l, const float* __restrict__ W1r,
                            const float* __restrict__ W2l, const float* __restrict__ W2r,
                            ushort* __restrict__ w1lp, ushort* __restrict__ w1rp,
                            ushort* __restrict__ w2lp, ushort* __restrict__ w2rp) {
    int blk = blockIdx.x;
    const float* W;
    ushort* out;
    int N, frag0;
    if (blk < 8)       { W = W1l; out = w1lp; N = 128; frag0 = blk * 4; }
    else if (blk < 16) { W = W1r; out = w1rp; N = 128; frag0 = (blk - 8) * 4; }
    else if (blk < 20) { W = W2l; out = w2lp; N = 64;  frag0 = (blk - 16) * 4; }
    else               { W = W2r; out = w2rp; N = 64;  frag0 = (blk - 20) * 4; }
    int lane = threadIdx.x & 63;
    int frag = frag0 + (threadIdx.x >> 6);
    int NT = N >> 4;
    int ktile = frag / NT, ntile = frag - ktile * NT;
    int k = ktile * 32 + (lane >> 4) * 8;
    int n = ntile * 16 + (lane & 15);
    ushort tmp[8];
#pragma unroll
    for (int j = 0; j < 8; ++j) tmp[j] = f2bf(W[(k + j) * N + n]);
    uint4 o;
    o.x = (unsigned)tmp[0] | ((unsigned)tmp[1] << 16);
    o.y = (unsigned)tmp[2] | ((unsigned)tmp[3] << 16);
    o.z = (unsigned)tmp[4] | ((unsigned)tmp[5] << 16);
    o.w = (unsigned)tmp[6] | ((unsigned)tmp[7] << 16);
    *(uint4*)&out[(frag * 64 + lane) * 8] = o;
}

// ---------------------------------------------------------------------------
// Coarse histogram: counts per 128-node dst block, LDS-privatized.
// ---------------------------------------------------------------------------
__global__ __launch_bounds__(256) void chist_kernel(const int* __restrict__ dst,
                                                    int* __restrict__ cb) {
    __shared__ int h[KB];
    int t = threadIdx.x;
    for (int i = t; i < KB; i += 256) h[i] = 0;
    __syncthreads();
    for (int e = blockIdx.x * 256 + t; e < NE; e += gridDim.x * 256)
        atomicAdd(&h[dst[e] >> BSH], 1);
    __syncthreads();
    for (int i = t; i < KB; i += 256)
        if (h[i]) atomicAdd(&cb[i], h[i]);
}

// ---------------------------------------------------------------------------
// Scan KB counts -> exclusive offsets in cb (cb[KB]=NE) and cursor copy in cc.
// ---------------------------------------------------------------------------
__global__ __launch_bounds__(1024) void cscan_kernel(int* __restrict__ cb,
                                                     int* __restrict__ cc) {
    __shared__ int s[1024];
    int t = threadIdx.x;
    s[t] = (t < KB) ? cb[t] : 0;
    __syncthreads();
    for (int off = 1; off < 1024; off <<= 1) {
        int v = (t >= off) ? s[t - off] : 0;
        __syncthreads();
        s[t] += v;
        __syncthreads();
    }
    if (t < KB) {
        int excl = (t == 0) ? 0 : s[t - 1];
        cb[t] = excl;
        cc[t] = excl;
    }
    if (t == KB - 1) cb[KB] = s[t];
}

// ---------------------------------------------------------------------------
// Coarse partition with block-aggregated reservation (fixes R5's per-address
// atomic serialization: 1.6M global atomics on 782 cursors -> 78.2K).
// Each block: LDS hist over its 16000 edges -> one global atomicAdd per
// nonempty bucket to reserve a contiguous range -> LDS-cursor placement.
// Per-bucket runs are ~20 consecutive entries -> write lines fill well.
// ---------------------------------------------------------------------------
__global__ __launch_bounds__(1024) void cpart_kernel(const int* __restrict__ src,
                                                     const int* __restrict__ dst,
                                                     int* __restrict__ cc,
                                                     unsigned* __restrict__ stage) {
    __shared__ int hist[KB];
    __shared__ int cur[KB];
    int t = threadIdx.x;
    int e0 = blockIdx.x * (NE / PBLK);
    int e1 = e0 + (NE / PBLK);
    for (int i = t; i < KB; i += 1024) hist[i] = 0;
    __syncthreads();
    for (int e = e0 + t; e < e1; e += 1024)
        atomicAdd(&hist[dst[e] >> BSH], 1);
    __syncthreads();
    for (int i = t; i < KB; i += 1024) {
        int c = hist[i];
        cur[i] = c ? atomicAdd(&cc[i], c) : 0;
    }
    __syncthreads();
    for (int e = e0 + t; e < e1; e += 1024) {
        int d = dst[e];
        int p = atomicAdd(&cur[d >> BSH], 1);
        stage[p] = ((unsigned)(d & 127) << 17) | (unsigned)src[e];
    }
}

// ---------------------------------------------------------------------------
// Fused aggregation, layer 1: one block per coarse bucket. Build local CSR in
// LDS (hist/scan/scatter), then half-wave per node gathers bf16 x rows
// (uint2/lane, 256B/edge) and writes mean bf16. No global CSR at all.
// ---------------------------------------------------------------------------
__global__ __launch_bounds__(256) void agg1f_kernel(const unsigned* __restrict__ stage,
                                                    const int* __restrict__ cb,
                                                    const ushort* __restrict__ xb,
                                                    ushort* __restrict__ meanb) {
    __shared__ unsigned raw[MAXB];
    __shared__ unsigned ssrc[MAXB];
    __shared__ int sc[128];
    __shared__ int loff[129];
    __shared__ int lcur[128];
    int t = threadIdx.x;
    int b = blockIdx.x;
    int estart = cb[b], eend = cb[b + 1];
    int cnt = eend - estart;

    for (int i = t; i < cnt; i += 256) raw[i] = stage[estart + i];
    if (t < 128) lcur[t] = 0;
    __syncthreads();
    for (int i = t; i < cnt; i += 256) atomicAdd(&lcur[raw[i] >> 17], 1);
    __syncthreads();
    if (t < 128) sc[t] = lcur[t];
    __syncthreads();
    for (int off = 1; off < 128; off <<= 1) {
        int v = (t < 128 && t >= off) ? sc[t - off] : 0;
        __syncthreads();
        if (t < 128) sc[t] += v;
        __syncthreads();
    }
    if (t < 128) {
        int excl = (t == 0) ? 0 : sc[t - 1];
        loff[t] = excl;
        lcur[t] = excl;
    }
    if (t == 127) loff[128] = sc[127];
    __syncthreads();
    for (int i = t; i < cnt; i += 256) {
        unsigned v = raw[i];
        int p = atomicAdd(&lcur[v >> 17], 1);
        ssrc[p] = v & 0x1FFFFu;
    }
    __syncthreads();

    int hw = t >> 5, l5 = t & 31;
    int node0 = b << BSH;
    int nmax = min(128, NN - node0);
    const unsigned* xbu = (const unsigned*)xb;
    int co = 2 * l5;
    for (int nl = hw; nl < nmax; nl += 8) {
        int s0 = loff[nl], s1 = loff[nl + 1];
        float a0 = 0.f, a1 = 0.f, a2 = 0.f, a3 = 0.f;
        int e = s0;
        for (; e + 4 <= s1; e += 4) {
            int q0 = ssrc[e + 0] * 64;
            int q1 = ssrc[e + 1] * 64;
            int q2 = ssrc[e + 2] * 64;
            int q3 = ssrc[e + 3] * 64;
            uint2 u0 = *(const uint2*)&xbu[q0 + co];
            uint2 u1 = *(const uint2*)&xbu[q1 + co];
            uint2 u2 = *(const uint2*)&xbu[q2 + co];
            uint2 u3 = *(const uint2*)&xbu[q3 + co];
            a0 += bflo(u0.x) + bflo(u1.x) + bflo(u2.x) + bflo(u3.x);
            a1 += bfhi(u0.x) + bfhi(u1.x) + bfhi(u2.x) + bfhi(u3.x);
            a2 += bflo(u0.y) + bflo(u1.y) + bflo(u2.y) + bflo(u3.y);
            a3 += bfhi(u0.y) + bfhi(u1.y) + bfhi(u2.y) + bfhi(u3.y);
        }
        for (; e < s1; ++e) {
            uint2 u = *(const uint2*)&xbu[ssrc[e] * 64 + co];
            a0 += bflo(u.x); a1 += bfhi(u.x); a2 += bflo(u.y); a3 += bfhi(u.y);
        }
        float inv = 1.0f / fmaxf((float)(s1 - s0), 1.0f);
        uint2 o;
        o.x = (unsigned)f2bf(a0 * inv) | ((unsigned)f2bf(a1 * inv) << 16);
        o.y = (unsigned)f2bf(a2 * inv) | ((unsigned)f2bf(a3 * inv) << 16);
        *(uint2*)&((unsigned*)meanb)[(node0 + nl) * 64 + co] = o;
    }
}

// ---------------------------------------------------------------------------
// Fused aggregation, layer 2: same local-CSR structure; gathers bf16 pl rows
// (uint/lane, 128B/edge, 12.8MB table), writes meanp fp32.
// ---------------------------------------------------------------------------
__global__ __launch_bounds__(256) void agg2f_kernel(const unsigned* __restrict__ stage,
                                                    const int* __restrict__ cb,
                                                    const ushort* __restrict__ pb,
                                                    float* __restrict__ meanp) {
    __shared__ unsigned raw[MAXB];
    __shared__ unsigned ssrc[MAXB];
    __shared__ int sc[128];
    __shared__ int loff[129];
    __shared__ int lcur[128];
    int t = threadIdx.x;
    int b = blockIdx.x;
    int estart = cb[b], eend = cb[b + 1];
    int cnt = eend - estart;

    for (int i = t; i < cnt; i += 256) raw[i] = stage[estart + i];
    if (t < 128) lcur[t] = 0;
    __syncthreads();
    for (int i = t; i < cnt; i += 256) atomicAdd(&lcur[raw[i] >> 17], 1);
    __syncthreads();
    if (t < 128) sc[t] = lcur[t];
    __syncthreads();
    for (int off = 1; off < 128; off <<= 1) {
        int v = (t < 128 && t >= off) ? sc[t - off] : 0;
        __syncthreads();
        if (t < 128) sc[t] += v;
        __syncthreads();
    }
    if (t < 128) {
        int excl = (t == 0) ? 0 : sc[t - 1];
        loff[t] = excl;
        lcur[t] = excl;
    }
    if (t == 127) loff[128] = sc[127];
    __syncthreads();
    for (int i = t; i < cnt; i += 256) {
        unsigned v = raw[i];
        int p = atomicAdd(&lcur[v >> 17], 1);
        ssrc[p] = v & 0x1FFFFu;
    }
    __syncthreads();

    int hw = t >> 5, l5 = t & 31;
    int node0 = b << BSH;
    int nmax = min(128, NN - node0);
    const unsigned* pbu = (const unsigned*)pb;
    for (int nl = hw; nl < nmax; nl += 8) {
        int s0 = loff[nl], s1 = loff[nl + 1];
        float a0 = 0.f, a1 = 0.f;
        int e = s0;
        for (; e + 4 <= s1; e += 4) {
            unsigned u0 = pbu[ssrc[e + 0] * 32 + l5];
            unsigned u1 = pbu[ssrc[e + 1] * 32 + l5];
            unsigned u2 = pbu[ssrc[e + 2] * 32 + l5];
            unsigned u3 = pbu[ssrc[e + 3] * 32 + l5];
            a0 += bflo(u0) + bflo(u1) + bflo(u2) + bflo(u3);
            a1 += bfhi(u0) + bfhi(u1) + bfhi(u2) + bfhi(u3);
        }
        for (; e < s1; ++e) {
            unsigned u = pbu[ssrc[e] * 32 + l5];
            a0 += bflo(u); a1 += bfhi(u);
        }
        float inv = 1.0f / fmaxf((float)(s1 - s0), 1.0f);
        float2 o = {a0 * inv, a1 * inv};
        *(float2*)&meanp[(node0 + nl) * 64 + 2 * l5] = o;
    }
}

// ---------------------------------------------------------------------------
// GEMM1 (MFMA): h = relu(mean@W1l + x@W1r + b1); hb = bf16(h); pb = bf16(h@W2l).
// ---------------------------------------------------------------------------
__global__ __launch_bounds__(256) void gemm1_kernel(const ushort* __restrict__ meanb,
                                                    const ushort* __restrict__ xb,
                                                    const ushort* __restrict__ w1lp,
                                                    const ushort* __restrict__ w1rp,
                                                    const float* __restrict__ b1,
                                                    const ushort* __restrict__ w2lp,
                                                    ushort* __restrict__ hb,
                                                    ushort* __restrict__ pb) {
    __shared__ ushort As[64 * 136];
    int t = threadIdx.x;
    int node0 = blockIdx.x * 64;
    int w = t >> 6, l = t & 63;
    int lrow = w * 16 + (l & 15);
    int lkq = (l >> 4) * 8;
    int cq = l & 15, rq = (l >> 4) * 4;

    f32x4 acc[8];
#pragma unroll
    for (int i = 0; i < 8; ++i) acc[i] = (f32x4){0.f, 0.f, 0.f, 0.f};

    {
        const uint4* g = (const uint4*)(meanb + (size_t)node0 * 128);
#pragma unroll
        for (int i = 0; i < 4; ++i) {
            int chunk = t + 256 * i;
            *(uint4*)&As[(chunk >> 4) * 136 + (chunk & 15) * 8] = g[chunk];
        }
    }
    __syncthreads();
#pragma unroll
    for (int kt = 0; kt < 4; ++kt) {
        bf16x8 a = *(const bf16x8*)&As[lrow * 136 + kt * 32 + lkq];
        const bf16x8* bp = (const bf16x8*)w1lp + (kt * 8) * 64 + l;
#pragma unroll
        for (int nt = 0; nt < 8; ++nt)
            acc[nt] = __builtin_amdgcn_mfma_f32_16x16x32_bf16(a, bp[nt * 64], acc[nt], 0, 0, 0);
    }
    __syncthreads();

    {
        const uint4* g = (const uint4*)(xb + (size_t)node0 * 128);
#pragma unroll
        for (int i = 0; i < 4; ++i) {
            int chunk = t + 256 * i;
            *(uint4*)&As[(chunk >> 4) * 136 + (chunk & 15) * 8] = g[chunk];
        }
    }
    __syncthreads();
#pragma unroll
    for (int kt = 0; kt < 4; ++kt) {
        bf16x8 a = *(const bf16x8*)&As[lrow * 136 + kt * 32 + lkq];
        const bf16x8* bp = (const bf16x8*)w1rp + (kt * 8) * 64 + l;
#pragma unroll
        for (int nt = 0; nt < 8; ++nt)
            acc[nt] = __builtin_amdgcn_mfma_f32_16x16x32_bf16(a, bp[nt * 64], acc[nt], 0, 0, 0);
    }
    __syncthreads();

#pragma unroll
    for (int nt = 0; nt < 8; ++nt) {
        int n = nt * 16 + cq;
        float bias = b1[n];
#pragma unroll
        for (int r = 0; r < 4; ++r) {
            float hv = fmaxf(acc[nt][r] + bias, 0.0f);
            As[(w * 16 + rq + r) * 136 + n] = f2bf(hv);
        }
    }
    __syncthreads();

    {
        uint4* g = (uint4*)(hb + (size_t)node0 * 128);
#pragma unroll
        for (int i = 0; i < 4; ++i) {
            int chunk = t + 256 * i;
            if (node0 + (chunk >> 4) < NN)
                g[chunk] = *(const uint4*)&As[(chunk >> 4) * 136 + (chunk & 15) * 8];
        }
    }

    f32x4 acc2[4];
#pragma unroll
    for (int i = 0; i < 4; ++i) acc2[i] = (f32x4){0.f, 0.f, 0.f, 0.f};
#pragma unroll
    for (int kt = 0; kt < 4; ++kt) {
        bf16x8 a = *(const bf16x8*)&As[lrow * 136 + kt * 32 + lkq];
        const bf16x8* bp = (const bf16x8*)w2lp + (kt * 4) * 64 + l;
#pragma unroll
        for (int nt = 0; nt < 4; ++nt)
            acc2[nt] = __builtin_amdgcn_mfma_f32_16x16x32_bf16(a, bp[nt * 64], acc2[nt], 0, 0, 0);
    }
    __syncthreads();

#pragma unroll
    for (int nt = 0; nt < 4; ++nt)
#pragma unroll
        for (int r = 0; r < 4; ++r)
            As[(w * 16 + rq + r) * 136 + nt * 16 + cq] = f2bf(acc2[nt][r]);
    __syncthreads();
    {
        uint4* g = (uint4*)(pb + (size_t)node0 * 64);
#pragma unroll
        for (int i = 0; i < 2; ++i) {
            int chunk = t + 256 * i;
            if (node0 + (chunk >> 3) < NN)
                g[chunk] = *(const uint4*)&As[(chunk >> 3) * 136 + (chunk & 7) * 8];
        }
    }
}

// ---------------------------------------------------------------------------
// GEMM2 (MFMA): out = meanp + hb@W2r + b2.
// ---------------------------------------------------------------------------
__global__ __launch_bounds__(256) void gemm2_kernel(const float* __restrict__ meanp,
                                                    const ushort* __restrict__ hb,
                                                    const ushort* __restrict__ w2rp,
                                                    const float* __restrict__ b2,
                                                    float* __restrict__ out) {
    __shared__ ushort As[64 * 136];
    int t = threadIdx.x;
    int node0 = blockIdx.x * 64;
    int w = t >> 6, l = t & 63;
    int lrow = w * 16 + (l & 15);
    int lkq = (l >> 4) * 8;
    int cq = l & 15, rq = (l >> 4) * 4;

    {
        const uint4* g = (const uint4*)(hb + (size_t)node0 * 128);
#pragma unroll
        for (int i = 0; i < 4; ++i) {
            int chunk = t + 256 * i;
            *(uint4*)&As[(chunk >> 4) * 136 + (chunk & 15) * 8] = g[chunk];
        }
    }
    __syncthreads();

    f32x4 acc[4];
#pragma unroll
    for (int i = 0; i < 4; ++i) acc[i] = (f32x4){0.f, 0.f, 0.f, 0.f};
#pragma unroll
    for (int kt = 0; kt < 4; ++kt) {
        bf16x8 a = *(const bf16x8*)&As[lrow * 136 + kt * 32 + lkq];
        const bf16x8* bp = (const bf16x8*)w2rp + (kt * 4) * 64 + l;
#pragma unroll
        for (int nt = 0; nt < 4; ++nt)
            acc[nt] = __builtin_amdgcn_mfma_f32_16x16x32_bf16(a, bp[nt * 64], acc[nt], 0, 0, 0);
    }

#pragma unroll
    for (int nt = 0; nt < 4; ++nt) {
        int n = nt * 16 + cq;
        float bias = b2[n];
#pragma unroll
        for (int r = 0; r < 4; ++r) {
            int row = node0 + w * 16 + rq + r;
            if (row < NN)
                out[(size_t)row * 64 + n] = acc[nt][r] + bias + meanp[(size_t)row * 64 + n];
        }
    }
}

extern "C" void kernel_launch(void* const* d_in, const int* in_sizes, int n_in,
                              void* d_out, int out_size, void* d_ws, size_t ws_size,
                              hipStream_t stream) {
    const float* x   = (const float*)d_in[0];
    const int*   ei  = (const int*)d_in[1];
    const float* W1l = (const float*)d_in[2];
    const float* W1r = (const float*)d_in[3];
    const float* b1  = (const float*)d_in[4];
    const float* W2l = (const float*)d_in[5];
    const float* W2r = (const float*)d_in[6];
    const float* b2  = (const float*)d_in[7];

    const int* src = ei;
    const int* dst = ei + NE;

    int*      ws_i  = (int*)d_ws;
    int*      cb    = ws_i + OFF_CB;
    int*      cc    = ws_i + OFF_CC;
    unsigned* stage = (unsigned*)(ws_i + OFF_STAGE);
    ushort*   xb    = (ushort*)(ws_i + OFF_XB);
    ushort*   meanb = (ushort*)(ws_i + OFF_MEANB);
    float*    meanp = (float*)(ws_i + OFF_MEANB);  // aliases meanb (disjoint lifetime)
    ushort*   hb    = (ushort*)(ws_i + OFF_HB);
    ushort*   pb    = (ushort*)(ws_i + OFF_PB);
    ushort*   w1lp  = (ushort*)(ws_i + OFF_W1LP);
    ushort*   w1rp  = (ushort*)(ws_i + OFF_W1RP);
    ushort*   w2lp  = (ushort*)(ws_i + OFF_W2LP);
    ushort*   w2rp  = (ushort*)(ws_i + OFF_W2RP);

    // Prep: zero coarse hist, convert x, pack weights, build coarse partition.
    hipMemsetAsync(cb, 0, 1024 * sizeof(int), stream);
    cvt_kernel<<<12500, 256, 0, stream>>>(x, xb);
    pack_kernel<<<24, 256, 0, stream>>>(W1l, W1r, W2l, W2r, w1lp, w1rp, w2lp, w2rp);
    chist_kernel<<<256, 256, 0, stream>>>(dst, cb);
    cscan_kernel<<<1, 1024, 0, stream>>>(cb, cc);
    cpart_kernel<<<PBLK, 1024, 0, stream>>>(src, dst, cc, stage);

    // Layer 1
    agg1f_kernel<<<KB, 256, 0, stream>>>(stage, cb, xb, meanb);
    gemm1_kernel<<<(NN + 63) / 64, 256, 0, stream>>>(meanb, xb, w1lp, w1rp, b1, w2lp, hb, pb);

    // Layer 2 (aggregation commuted past W2l)
    agg2f_kernel<<<KB, 256, 0, stream>>>(stage, cb, pb, meanp);
    gemm2_kernel<<<(NN + 63) / 64, 256, 0, stream>>>(meanp, hb, w2rp, b2, (float*)d_out);
}

// Round 7
// 280.523 us; speedup vs baseline: 2.3714x; 1.1678x over previous
//
#include <hip/hip_runtime.h>

#define NN 100000
#define NE 1600000
#define KB 782      // coarse buckets: ceil(100000/128)
#define BSH 7       // bucket = dst >> 7; 128 nodes per bucket
#define MAXB 4096   // fixed slots per bucket (mean 2046, max ~2250 — safe)
#define PBLK 200    // cpart blocks; NE/PBLK = 8000 edges per block

// Workspace layout in 4-byte units (total 25,650,176 uints = 102.6 MB):
#define OFF_CC    0            // 1024: per-bucket edge counts / reservation cursors
#define OFF_STAGE 1024         // KB*MAXB = 3,203,072: packed (dstLow<<17)|src, slotted per bucket
#define OFF_XB    3204096      // x bf16 [100096,128]
#define OFF_XF8   9610240      // x fp8 [100096,128] (12.8MB); pb bf16 [100096,64] aliases (xf8 dead after agg1f)
#define OFF_MEANB 12813312     // mean bf16 [100096,128]; meanp fp32 [100096,64] aliases
#define OFF_HB    19219456     // h bf16 [100096,128]
#define OFF_W1LP  25625600     // packed weights bf16
#define OFF_W1RP  (25625600 + 8192)
#define OFF_W2LP  (25625600 + 16384)
#define OFF_W2RP  (25625600 + 20480)

typedef __bf16 bf16x8 __attribute__((ext_vector_type(8)));
typedef float f32x4 __attribute__((ext_vector_type(4)));
typedef float f32x2 __attribute__((ext_vector_type(2)));

static __device__ __forceinline__ ushort f2bf(float f) {
    unsigned u = __float_as_uint(f);
    return (ushort)((u + 0x7fffu + ((u >> 16) & 1u)) >> 16);
}
static __device__ __forceinline__ float bflo(unsigned u) { return __uint_as_float(u << 16); }
static __device__ __forceinline__ float bfhi(unsigned u) { return __uint_as_float(u & 0xffff0000u); }

// ---------------------------------------------------------------------------
// x (fp32) -> xb (bf16, for gemm1) and xf8 (fp8 e4m3, for agg1 gather).
// One float4 per thread.
// ---------------------------------------------------------------------------
__global__ void cvt_kernel(const float* __restrict__ x, ushort* __restrict__ xb,
                           unsigned* __restrict__ xf8) {
    int i = blockIdx.x * 256 + threadIdx.x;  // covers NN*128/4 = 3.2M
    float4 v = ((const float4*)x)[i];
    uint2 o;
    o.x = (unsigned)f2bf(v.x) | ((unsigned)f2bf(v.y) << 16);
    o.y = (unsigned)f2bf(v.z) | ((unsigned)f2bf(v.w) << 16);
    ((uint2*)xb)[i] = o;
    int p8 = __builtin_amdgcn_cvt_pk_fp8_f32(v.x, v.y, 0, false);
    p8 = __builtin_amdgcn_cvt_pk_fp8_f32(v.z, v.w, p8, true);
    xf8[i] = (unsigned)p8;
}

// ---------------------------------------------------------------------------
// Pack all 4 weight matrices fp32 -> bf16 MFMA B-frag layout.
// ---------------------------------------------------------------------------
__global__ void pack_kernel(const float* __restrict__ W1l, const float* __restrict__ W1r,
                            const float* __restrict__ W2l, const float* __restrict__ W2r,
                            ushort* __restrict__ w1lp, ushort* __restrict__ w1rp,
                            ushort* __restrict__ w2lp, ushort* __restrict__ w2rp) {
    int blk = blockIdx.x;
    const float* W;
    ushort* out;
    int N, frag0;
    if (blk < 8)       { W = W1l; out = w1lp; N = 128; frag0 = blk * 4; }
    else if (blk < 16) { W = W1r; out = w1rp; N = 128; frag0 = (blk - 8) * 4; }
    else if (blk < 20) { W = W2l; out = w2lp; N = 64;  frag0 = (blk - 16) * 4; }
    else               { W = W2r; out = w2rp; N = 64;  frag0 = (blk - 20) * 4; }
    int lane = threadIdx.x & 63;
    int frag = frag0 + (threadIdx.x >> 6);
    int NT = N >> 4;
    int ktile = frag / NT, ntile = frag - ktile * NT;
    int k = ktile * 32 + (lane >> 4) * 8;
    int n = ntile * 16 + (lane & 15);
    ushort tmp[8];
#pragma unroll
    for (int j = 0; j < 8; ++j) tmp[j] = f2bf(W[(k + j) * N + n]);
    uint4 o;
    o.x = (unsigned)tmp[0] | ((unsigned)tmp[1] << 16);
    o.y = (unsigned)tmp[2] | ((unsigned)tmp[3] << 16);
    o.z = (unsigned)tmp[4] | ((unsigned)tmp[5] << 16);
    o.w = (unsigned)tmp[6] | ((unsigned)tmp[7] << 16);
    *(uint4*)&out[(frag * 64 + lane) * 8] = o;
}

// ---------------------------------------------------------------------------
// Coarse partition, fixed-capacity slots (no pre-scan needed). Block-level
// LDS histogram -> one global atomicAdd per (block,bucket) reserves a run ->
// LDS-cursor placement at stage[bucket*MAXB + pos].
// ---------------------------------------------------------------------------
__global__ __launch_bounds__(1024) void cpart_kernel(const int* __restrict__ src,
                                                     const int* __restrict__ dst,
                                                     int* __restrict__ cc,
                                                     unsigned* __restrict__ stage) {
    __shared__ int hist[KB];
    __shared__ int cur[KB];
    int t = threadIdx.x;
    int e0 = blockIdx.x * (NE / PBLK);
    int e1 = e0 + (NE / PBLK);
    for (int i = t; i < KB; i += 1024) hist[i] = 0;
    __syncthreads();
    for (int e = e0 + t; e < e1; e += 1024)
        atomicAdd(&hist[dst[e] >> BSH], 1);
    __syncthreads();
    for (int i = t; i < KB; i += 1024) {
        int c = hist[i];
        cur[i] = c ? atomicAdd(&cc[i], c) : 0;
    }
    __syncthreads();
    for (int e = e0 + t; e < e1; e += 1024) {
        int d = dst[e];
        int bkt = d >> BSH;
        int p = atomicAdd(&cur[bkt], 1);
        if (p < MAXB)
            stage[bkt * MAXB + p] = ((unsigned)(d & 127) << 17) | (unsigned)src[e];
    }
}

// ---------------------------------------------------------------------------
// Fused aggregation, layer 1 (fp8 gather): one block per coarse bucket.
// Local CSR in LDS (stage read twice from global — L2-warm — so no raw
// buffer; LDS ~17.5KB -> 8 blocks/CU). Quarter-wave (16 lanes) per node,
// lane owns 8 channels (uint2 = 8 fp8 = 128B/row coalesced). HW fp8 decode.
// Writes mean bf16.
// ---------------------------------------------------------------------------
__global__ __launch_bounds__(256) void agg1f_kernel(const unsigned* __restrict__ stage,
                                                    const int* __restrict__ cc,
                                                    const unsigned* __restrict__ xf8,
                                                    ushort* __restrict__ meanb) {
    __shared__ unsigned ssrc[MAXB];
    __shared__ int sc[128];
    __shared__ int loff[129];
    __shared__ int lcur[128];
    int t = threadIdx.x;
    int b = blockIdx.x;
    const unsigned* st = stage + b * MAXB;
    int cnt = min(cc[b], MAXB);

    if (t < 128) lcur[t] = 0;
    __syncthreads();
    for (int i = t; i < cnt; i += 256) atomicAdd(&lcur[st[i] >> 17], 1);
    __syncthreads();
    if (t < 128) sc[t] = lcur[t];
    __syncthreads();
    for (int off = 1; off < 128; off <<= 1) {
        int v = (t < 128 && t >= off) ? sc[t - off] : 0;
        __syncthreads();
        if (t < 128) sc[t] += v;
        __syncthreads();
    }
    if (t < 128) {
        int excl = (t == 0) ? 0 : sc[t - 1];
        loff[t] = excl;
        lcur[t] = excl;
    }
    if (t == 127) loff[128] = sc[127];
    __syncthreads();
    for (int i = t; i < cnt; i += 256) {
        unsigned v = st[i];
        int p = atomicAdd(&lcur[v >> 17], 1);
        ssrc[p] = v & 0x1FFFFu;
    }
    __syncthreads();

    int qw = t >> 4, l4 = t & 15;
    int node0 = b << BSH;
    int nmax = min(128, NN - node0);
    const uint2* xv = (const uint2*)xf8;  // row = 16 uint2 (128 fp8)
    for (int nl = qw; nl < nmax; nl += 16) {
        int s0 = loff[nl], s1 = loff[nl + 1];
        float a0 = 0.f, a1 = 0.f, a2 = 0.f, a3 = 0.f;
        float a4 = 0.f, a5 = 0.f, a6 = 0.f, a7 = 0.f;
        int e = s0;
        for (; e + 4 <= s1; e += 4) {
            uint2 u0 = xv[ssrc[e + 0] * 16 + l4];
            uint2 u1 = xv[ssrc[e + 1] * 16 + l4];
            uint2 u2 = xv[ssrc[e + 2] * 16 + l4];
            uint2 u3 = xv[ssrc[e + 3] * 16 + l4];
#pragma unroll
            for (int j = 0; j < 4; ++j) {
                unsigned lo = (j == 0) ? u0.x : (j == 1) ? u1.x : (j == 2) ? u2.x : u3.x;
                unsigned hi = (j == 0) ? u0.y : (j == 1) ? u1.y : (j == 2) ? u2.y : u3.y;
                f32x2 p0 = __builtin_amdgcn_cvt_pk_f32_fp8(lo, false);
                f32x2 p1 = __builtin_amdgcn_cvt_pk_f32_fp8(lo, true);
                f32x2 p2 = __builtin_amdgcn_cvt_pk_f32_fp8(hi, false);
                f32x2 p3 = __builtin_amdgcn_cvt_pk_f32_fp8(hi, true);
                a0 += p0.x; a1 += p0.y; a2 += p1.x; a3 += p1.y;
                a4 += p2.x; a5 += p2.y; a6 += p3.x; a7 += p3.y;
            }
        }
        for (; e < s1; ++e) {
            uint2 u = xv[ssrc[e] * 16 + l4];
            f32x2 p0 = __builtin_amdgcn_cvt_pk_f32_fp8(u.x, false);
            f32x2 p1 = __builtin_amdgcn_cvt_pk_f32_fp8(u.x, true);
            f32x2 p2 = __builtin_amdgcn_cvt_pk_f32_fp8(u.y, false);
            f32x2 p3 = __builtin_amdgcn_cvt_pk_f32_fp8(u.y, true);
            a0 += p0.x; a1 += p0.y; a2 += p1.x; a3 += p1.y;
            a4 += p2.x; a5 += p2.y; a6 += p3.x; a7 += p3.y;
        }
        float inv = 1.0f / fmaxf((float)(s1 - s0), 1.0f);
        uint4 o;
        o.x = (unsigned)f2bf(a0 * inv) | ((unsigned)f2bf(a1 * inv) << 16);
        o.y = (unsigned)f2bf(a2 * inv) | ((unsigned)f2bf(a3 * inv) << 16);
        o.z = (unsigned)f2bf(a4 * inv) | ((unsigned)f2bf(a5 * inv) << 16);
        o.w = (unsigned)f2bf(a6 * inv) | ((unsigned)f2bf(a7 * inv) << 16);
        *(uint4*)&meanb[(node0 + nl) * 128 + 8 * l4] = o;
    }
}

// ---------------------------------------------------------------------------
// Fused aggregation, layer 2: same local-CSR (reduced LDS); half-wave per
// node gathers bf16 pl rows (uint/lane, 128B/edge), writes meanp fp32.
// ---------------------------------------------------------------------------
__global__ __launch_bounds__(256) void agg2f_kernel(const unsigned* __restrict__ stage,
                                                    const int* __restrict__ cc,
                                                    const ushort* __restrict__ pb,
                                                    float* __restrict__ meanp) {
    __shared__ unsigned ssrc[MAXB];
    __shared__ int sc[128];
    __shared__ int loff[129];
    __shared__ int lcur[128];
    int t = threadIdx.x;
    int b = blockIdx.x;
    const unsigned* st = stage + b * MAXB;
    int cnt = min(cc[b], MAXB);

    if (t < 128) lcur[t] = 0;
    __syncthreads();
    for (int i = t; i < cnt; i += 256) atomicAdd(&lcur[st[i] >> 17], 1);
    __syncthreads();
    if (t < 128) sc[t] = lcur[t];
    __syncthreads();
    for (int off = 1; off < 128; off <<= 1) {
        int v = (t < 128 && t >= off) ? sc[t - off] : 0;
        __syncthreads();
        if (t < 128) sc[t] += v;
        __syncthreads();
    }
    if (t < 128) {
        int excl = (t == 0) ? 0 : sc[t - 1];
        loff[t] = excl;
        lcur[t] = excl;
    }
    if (t == 127) loff[128] = sc[127];
    __syncthreads();
    for (int i = t; i < cnt; i += 256) {
        unsigned v = st[i];
        int p = atomicAdd(&lcur[v >> 17], 1);
        ssrc[p] = v & 0x1FFFFu;
    }
    __syncthreads();

    int hw = t >> 5, l5 = t & 31;
    int node0 = b << BSH;
    int nmax = min(128, NN - node0);
    const unsigned* pbu = (const unsigned*)pb;
    for (int nl = hw; nl < nmax; nl += 8) {
        int s0 = loff[nl], s1 = loff[nl + 1];
        float a0 = 0.f, a1 = 0.f;
        int e = s0;
        for (; e + 4 <= s1; e += 4) {
            unsigned u0 = pbu[ssrc[e + 0] * 32 + l5];
            unsigned u1 = pbu[ssrc[e + 1] * 32 + l5];
            unsigned u2 = pbu[ssrc[e + 2] * 32 + l5];
            unsigned u3 = pbu[ssrc[e + 3] * 32 + l5];
            a0 += bflo(u0) + bflo(u1) + bflo(u2) + bflo(u3);
            a1 += bfhi(u0) + bfhi(u1) + bfhi(u2) + bfhi(u3);
        }
        for (; e < s1; ++e) {
            unsigned u = pbu[ssrc[e] * 32 + l5];
            a0 += bflo(u); a1 += bfhi(u);
        }
        float inv = 1.0f / fmaxf((float)(s1 - s0), 1.0f);
        float2 o = {a0 * inv, a1 * inv};
        *(float2*)&meanp[(node0 + nl) * 64 + 2 * l5] = o;
    }
}

// ---------------------------------------------------------------------------
// GEMM1 (MFMA): h = relu(mean@W1l + x@W1r + b1); hb = bf16(h); pb = bf16(h@W2l).
// ---------------------------------------------------------------------------
__global__ __launch_bounds__(256) void gemm1_kernel(const ushort* __restrict__ meanb,
                                                    const ushort* __restrict__ xb,
                                                    const ushort* __restrict__ w1lp,
                                                    const ushort* __restrict__ w1rp,
                                                    const float* __restrict__ b1,
                                                    const ushort* __restrict__ w2lp,
                                                    ushort* __restrict__ hb,
                                                    ushort* __restrict__ pb) {
    __shared__ ushort As[64 * 136];
    int t = threadIdx.x;
    int node0 = blockIdx.x * 64;
    int w = t >> 6, l = t & 63;
    int lrow = w * 16 + (l & 15);
    int lkq = (l >> 4) * 8;
    int cq = l & 15, rq = (l >> 4) * 4;

    f32x4 acc[8];
#pragma unroll
    for (int i = 0; i < 8; ++i) acc[i] = (f32x4){0.f, 0.f, 0.f, 0.f};

    {
        const uint4* g = (const uint4*)(meanb + (size_t)node0 * 128);
#pragma unroll
        for (int i = 0; i < 4; ++i) {
            int chunk = t + 256 * i;
            *(uint4*)&As[(chunk >> 4) * 136 + (chunk & 15) * 8] = g[chunk];
        }
    }
    __syncthreads();
#pragma unroll
    for (int kt = 0; kt < 4; ++kt) {
        bf16x8 a = *(const bf16x8*)&As[lrow * 136 + kt * 32 + lkq];
        const bf16x8* bp = (const bf16x8*)w1lp + (kt * 8) * 64 + l;
#pragma unroll
        for (int nt = 0; nt < 8; ++nt)
            acc[nt] = __builtin_amdgcn_mfma_f32_16x16x32_bf16(a, bp[nt * 64], acc[nt], 0, 0, 0);
    }
    __syncthreads();

    {
        const uint4* g = (const uint4*)(xb + (size_t)node0 * 128);
#pragma unroll
        for (int i = 0; i < 4; ++i) {
            int chunk = t + 256 * i;
            *(uint4*)&As[(chunk >> 4) * 136 + (chunk & 15) * 8] = g[chunk];
        }
    }
    __syncthreads();
#pragma unroll
    for (int kt = 0; kt < 4; ++kt) {
        bf16x8 a = *(const bf16x8*)&As[lrow * 136 + kt * 32 + lkq];
        const bf16x8* bp = (const bf16x8*)w1rp + (kt * 8) * 64 + l;
#pragma unroll
        for (int nt = 0; nt < 8; ++nt)
            acc[nt] = __builtin_amdgcn_mfma_f32_16x16x32_bf16(a, bp[nt * 64], acc[nt], 0, 0, 0);
    }
    __syncthreads();

#pragma unroll
    for (int nt = 0; nt < 8; ++nt) {
        int n = nt * 16 + cq;
        float bias = b1[n];
#pragma unroll
        for (int r = 0; r < 4; ++r) {
            float hv = fmaxf(acc[nt][r] + bias, 0.0f);
            As[(w * 16 + rq + r) * 136 + n] = f2bf(hv);
        }
    }
    __syncthreads();

    {
        uint4* g = (uint4*)(hb + (size_t)node0 * 128);
#pragma unroll
        for (int i = 0; i < 4; ++i) {
            int chunk = t + 256 * i;
            if (node0 + (chunk >> 4) < NN)
                g[chunk] = *(const uint4*)&As[(chunk >> 4) * 136 + (chunk & 15) * 8];
        }
    }

    f32x4 acc2[4];
#pragma unroll
    for (int i = 0; i < 4; ++i) acc2[i] = (f32x4){0.f, 0.f, 0.f, 0.f};
#pragma unroll
    for (int kt = 0; kt < 4; ++kt) {
        bf16x8 a = *(const bf16x8*)&As[lrow * 136 + kt * 32 + lkq];
        const bf16x8* bp = (const bf16x8*)w2lp + (kt * 4) * 64 + l;
#pragma unroll
        for (int nt = 0; nt < 4; ++nt)
            acc2[nt] = __builtin_amdgcn_mfma_f32_16x16x32_bf16(a, bp[nt * 64], acc2[nt], 0, 0, 0);
    }
    __syncthreads();

#pragma unroll
    for (int nt = 0; nt < 4; ++nt)
#pragma unroll
        for (int r = 0; r < 4; ++r)
            As[(w * 16 + rq + r) * 136 + nt * 16 + cq] = f2bf(acc2[nt][r]);
    __syncthreads();
    {
        uint4* g = (uint4*)(pb + (size_t)node0 * 64);
#pragma unroll
        for (int i = 0; i < 2; ++i) {
            int chunk = t + 256 * i;
            if (node0 + (chunk >> 3) < NN)
                g[chunk] = *(const uint4*)&As[(chunk >> 3) * 136 + (chunk & 7) * 8];
        }
    }
}

// ---------------------------------------------------------------------------
// GEMM2 (MFMA): out = meanp + hb@W2r + b2.
// ---------------------------------------------------------------------------
__global__ __launch_bounds__(256) void gemm2_kernel(const float* __restrict__ meanp,
                                                    const ushort* __restrict__ hb,
                                                    const ushort* __restrict__ w2rp,
                                                    const float* __restrict__ b2,
                                                    float* __restrict__ out) {
    __shared__ ushort As[64 * 136];
    int t = threadIdx.x;
    int node0 = blockIdx.x * 64;
    int w = t >> 6, l = t & 63;
    int lrow = w * 16 + (l & 15);
    int lkq = (l >> 4) * 8;
    int cq = l & 15, rq = (l >> 4) * 4;

    {
        const uint4* g = (const uint4*)(hb + (size_t)node0 * 128);
#pragma unroll
        for (int i = 0; i < 4; ++i) {
            int chunk = t + 256 * i;
            *(uint4*)&As[(chunk >> 4) * 136 + (chunk & 15) * 8] = g[chunk];
        }
    }
    __syncthreads();

    f32x4 acc[4];
#pragma unroll
    for (int i = 0; i < 4; ++i) acc[i] = (f32x4){0.f, 0.f, 0.f, 0.f};
#pragma unroll
    for (int kt = 0; kt < 4; ++kt) {
        bf16x8 a = *(const bf16x8*)&As[lrow * 136 + kt * 32 + lkq];
        const bf16x8* bp = (const bf16x8*)w2rp + (kt * 4) * 64 + l;
#pragma unroll
        for (int nt = 0; nt < 4; ++nt)
            acc[nt] = __builtin_amdgcn_mfma_f32_16x16x32_bf16(a, bp[nt * 64], acc[nt], 0, 0, 0);
    }

#pragma unroll
    for (int nt = 0; nt < 4; ++nt) {
        int n = nt * 16 + cq;
        float bias = b2[n];
#pragma unroll
        for (int r = 0; r < 4; ++r) {
            int row = node0 + w * 16 + rq + r;
            if (row < NN)
                out[(size_t)row * 64 + n] = acc[nt][r] + bias + meanp[(size_t)row * 64 + n];
        }
    }
}

extern "C" void kernel_launch(void* const* d_in, const int* in_sizes, int n_in,
                              void* d_out, int out_size, void* d_ws, size_t ws_size,
                              hipStream_t stream) {
    const float* x   = (const float*)d_in[0];
    const int*   ei  = (const int*)d_in[1];
    const float* W1l = (const float*)d_in[2];
    const float* W1r = (const float*)d_in[3];
    const float* b1  = (const float*)d_in[4];
    const float* W2l = (const float*)d_in[5];
    const float* W2r = (const float*)d_in[6];
    const float* b2  = (const float*)d_in[7];

    const int* src = ei;
    const int* dst = ei + NE;

    int*      ws_i  = (int*)d_ws;
    int*      cc    = ws_i + OFF_CC;
    unsigned* stage = (unsigned*)(ws_i + OFF_STAGE);
    ushort*   xb    = (ushort*)(ws_i + OFF_XB);
    unsigned* xf8   = (unsigned*)(ws_i + OFF_XF8);
    ushort*   pb    = (ushort*)(ws_i + OFF_XF8);   // aliases xf8 (disjoint lifetime)
    ushort*   meanb = (ushort*)(ws_i + OFF_MEANB);
    float*    meanp = (float*)(ws_i + OFF_MEANB);  // aliases meanb (disjoint lifetime)
    ushort*   hb    = (ushort*)(ws_i + OFF_HB);
    ushort*   w1lp  = (ushort*)(ws_i + OFF_W1LP);
    ushort*   w1rp  = (ushort*)(ws_i + OFF_W1RP);
    ushort*   w2lp  = (ushort*)(ws_i + OFF_W2LP);
    ushort*   w2rp  = (ushort*)(ws_i + OFF_W2RP);

    // Prep: zero cursors, convert x (bf16+fp8), pack weights, coarse partition.
    hipMemsetAsync(cc, 0, 1024 * sizeof(int), stream);
    cvt_kernel<<<12500, 256, 0, stream>>>(x, xb, xf8);
    pack_kernel<<<24, 256, 0, stream>>>(W1l, W1r, W2l, W2r, w1lp, w1rp, w2lp, w2rp);
    cpart_kernel<<<PBLK, 1024, 0, stream>>>(src, dst, cc, stage);

    // Layer 1
    agg1f_kernel<<<KB, 256, 0, stream>>>(stage, cc, xf8, meanb);
    gemm1_kernel<<<(NN + 63) / 64, 256, 0, stream>>>(meanb, xb, w1lp, w1rp, b1, w2lp, hb, pb);

    // Layer 2 (aggregation commuted past W2l)
    agg2f_kernel<<<KB, 256, 0, stream>>>(stage, cc, pb, meanp);
    gemm2_kernel<<<(NN + 63) / 64, 256, 0, stream>>>(meanp, hb, w2rp, b2, (float*)d_out);
}

// Round 8
// 270.974 us; speedup vs baseline: 2.4550x; 1.0352x over previous
//
#include <hip/hip_runtime.h>

#define NN 100000
#define NE 1600000
#define KB 782      // coarse buckets: ceil(100000/128)
#define BSH 7       // bucket = dst >> 7; 128 nodes per bucket
#define MAXB 4096   // fixed slots per bucket (mean 2046, max ~2250 — safe)
#define PBLK 200    // cpart blocks; NE/PBLK = 8000 edges per block

// Workspace layout in 4-byte units (total 25,850,368 uints = 103.4 MB):
#define OFF_CC    0            // 1024: per-bucket edge counts
#define OFF_RST   1024         // 100096: per-node edge-range start (global slot index)
#define OFF_RDG   101120       // 100096: per-node degree
#define OFF_STAGE 201216       // KB*MAXB: packed (dstLow<<17)|src, slotted; node-sorted src after sort_kernel
#define OFF_XB    3404288      // x bf16 [100096,128]
#define OFF_XF8   9810432      // x fp8 [100096,128]; pb bf16 [100096,64] aliases (xf8 dead after agg1g)
#define OFF_MEANB 13013504     // mean bf16 [100096,128]; meanp fp32 [100096,64] aliases
#define OFF_HB    19419648     // h bf16 [100096,128]
#define OFF_W1LP  25825792     // packed weights bf16
#define OFF_W1RP  (25825792 + 8192)
#define OFF_W2LP  (25825792 + 16384)
#define OFF_W2RP  (25825792 + 20480)

typedef __bf16 bf16x8 __attribute__((ext_vector_type(8)));
typedef float f32x4 __attribute__((ext_vector_type(4)));
typedef float f32x2 __attribute__((ext_vector_type(2)));

static __device__ __forceinline__ ushort f2bf(float f) {
    unsigned u = __float_as_uint(f);
    return (ushort)((u + 0x7fffu + ((u >> 16) & 1u)) >> 16);
}
static __device__ __forceinline__ float bflo(unsigned u) { return __uint_as_float(u << 16); }
static __device__ __forceinline__ float bfhi(unsigned u) { return __uint_as_float(u & 0xffff0000u); }

// ---------------------------------------------------------------------------
// x (fp32) -> xb (bf16, for gemm1) and xf8 (fp8 e4m3, for agg1 gather).
// ---------------------------------------------------------------------------
__global__ void cvt_kernel(const float* __restrict__ x, ushort* __restrict__ xb,
                           unsigned* __restrict__ xf8) {
    int i = blockIdx.x * 256 + threadIdx.x;  // covers NN*128/4 = 3.2M
    float4 v = ((const float4*)x)[i];
    uint2 o;
    o.x = (unsigned)f2bf(v.x) | ((unsigned)f2bf(v.y) << 16);
    o.y = (unsigned)f2bf(v.z) | ((unsigned)f2bf(v.w) << 16);
    ((uint2*)xb)[i] = o;
    int p8 = __builtin_amdgcn_cvt_pk_fp8_f32(v.x, v.y, 0, false);
    p8 = __builtin_amdgcn_cvt_pk_fp8_f32(v.z, v.w, p8, true);
    xf8[i] = (unsigned)p8;
}

// ---------------------------------------------------------------------------
// Pack all 4 weight matrices fp32 -> bf16 MFMA B-frag layout.
// ---------------------------------------------------------------------------
__global__ void pack_kernel(const float* __restrict__ W1l, const float* __restrict__ W1r,
                            const float* __restrict__ W2l, const float* __restrict__ W2r,
                            ushort* __restrict__ w1lp, ushort* __restrict__ w1rp,
                            ushort* __restrict__ w2lp, ushort* __restrict__ w2rp) {
    int blk = blockIdx.x;
    const float* W;
    ushort* out;
    int N, frag0;
    if (blk < 8)       { W = W1l; out = w1lp; N = 128; frag0 = blk * 4; }
    else if (blk < 16) { W = W1r; out = w1rp; N = 128; frag0 = (blk - 8) * 4; }
    else if (blk < 20) { W = W2l; out = w2lp; N = 64;  frag0 = (blk - 16) * 4; }
    else               { W = W2r; out = w2rp; N = 64;  frag0 = (blk - 20) * 4; }
    int lane = threadIdx.x & 63;
    int frag = frag0 + (threadIdx.x >> 6);
    int NT = N >> 4;
    int ktile = frag / NT, ntile = frag - ktile * NT;
    int k = ktile * 32 + (lane >> 4) * 8;
    int n = ntile * 16 + (lane & 15);
    ushort tmp[8];
#pragma unroll
    for (int j = 0; j < 8; ++j) tmp[j] = f2bf(W[(k + j) * N + n]);
    uint4 o;
    o.x = (unsigned)tmp[0] | ((unsigned)tmp[1] << 16);
    o.y = (unsigned)tmp[2] | ((unsigned)tmp[3] << 16);
    o.z = (unsigned)tmp[4] | ((unsigned)tmp[5] << 16);
    o.w = (unsigned)tmp[6] | ((unsigned)tmp[7] << 16);
    *(uint4*)&out[(frag * 64 + lane) * 8] = o;
}

// ---------------------------------------------------------------------------
// Coarse partition, fixed-capacity slots. Block-level LDS histogram -> one
// global atomicAdd per (block,bucket) -> LDS-cursor placement.
// ---------------------------------------------------------------------------
__global__ __launch_bounds__(1024) void cpart_kernel(const int* __restrict__ src,
                                                     const int* __restrict__ dst,
                                                     int* __restrict__ cc,
                                                     unsigned* __restrict__ stage) {
    __shared__ int hist[KB];
    __shared__ int cur[KB];
    int t = threadIdx.x;
    int e0 = blockIdx.x * (NE / PBLK);
    int e1 = e0 + (NE / PBLK);
    for (int i = t; i < KB; i += 1024) hist[i] = 0;
    __syncthreads();
    for (int e = e0 + t; e < e1; e += 1024)
        atomicAdd(&hist[dst[e] >> BSH], 1);
    __syncthreads();
    for (int i = t; i < KB; i += 1024) {
        int c = hist[i];
        cur[i] = c ? atomicAdd(&cc[i], c) : 0;
    }
    __syncthreads();
    for (int e = e0 + t; e < e1; e += 1024) {
        int d = dst[e];
        int bkt = d >> BSH;
        int p = atomicAdd(&cur[bkt], 1);
        if (p < MAXB)
            stage[bkt * MAXB + p] = ((unsigned)(d & 127) << 17) | (unsigned)src[e];
    }
}

// ---------------------------------------------------------------------------
// Sort: one block per bucket. Build the local CSR in LDS (paid ONCE), write
// the node-sorted src list back into the stage slots in place, and emit
// global rstart/rdeg so the gather kernels need no LDS and no CSR build.
// ---------------------------------------------------------------------------
__global__ __launch_bounds__(256) void sort_kernel(unsigned* __restrict__ stage,
                                                   const int* __restrict__ cc,
                                                   int* __restrict__ rstart,
                                                   int* __restrict__ rdeg) {
    __shared__ unsigned ssrc[MAXB];
    __shared__ int sc[128];
    __shared__ int loff[129];
    __shared__ int lcur[128];
    int t = threadIdx.x;
    int b = blockIdx.x;
    unsigned* st = stage + b * MAXB;
    int cnt = min(cc[b], MAXB);

    if (t < 128) lcur[t] = 0;
    __syncthreads();
    for (int i = t; i < cnt; i += 256) atomicAdd(&lcur[st[i] >> 17], 1);
    __syncthreads();
    if (t < 128) sc[t] = lcur[t];
    __syncthreads();
    for (int off = 1; off < 128; off <<= 1) {
        int v = (t < 128 && t >= off) ? sc[t - off] : 0;
        __syncthreads();
        if (t < 128) sc[t] += v;
        __syncthreads();
    }
    if (t < 128) {
        int excl = (t == 0) ? 0 : sc[t - 1];
        loff[t] = excl;
        lcur[t] = excl;
    }
    if (t == 127) loff[128] = sc[127];
    __syncthreads();
    for (int i = t; i < cnt; i += 256) {
        unsigned v = st[i];
        int p = atomicAdd(&lcur[v >> 17], 1);
        ssrc[p] = v & 0x1FFFFu;
    }
    __syncthreads();
    for (int i = t; i < cnt; i += 256) st[i] = ssrc[i];
    int node0 = b << BSH;
    if (t < 128 && node0 + t < NN) {
        rstart[node0 + t] = b * MAXB + loff[t];
        rdeg[node0 + t] = loff[t + 1] - loff[t];
    }
}

// ---------------------------------------------------------------------------
// Layer-1 gather (fp8, zero LDS): quarter-wave (16 lanes) per node, lane owns
// 8 channels (uint2 = 8 fp8; 16 lanes x 8B = 128B coalesced row). Unroll-4
// edges. Grid 6250 x 256 = 100000 nodes exactly. Writes mean bf16.
// ---------------------------------------------------------------------------
__global__ __launch_bounds__(256) void agg1g_kernel(const unsigned* __restrict__ es,
                                                    const int* __restrict__ rstart,
                                                    const int* __restrict__ rdeg,
                                                    const unsigned* __restrict__ xf8,
                                                    ushort* __restrict__ meanb) {
    int t = threadIdx.x;
    int node = blockIdx.x * 16 + (t >> 4);
    int l4 = t & 15;
    int s0 = rstart[node];
    int deg = rdeg[node];
    const uint2* xv = (const uint2*)xf8;  // row = 16 uint2 (128 fp8)
    float a0 = 0.f, a1 = 0.f, a2 = 0.f, a3 = 0.f;
    float a4 = 0.f, a5 = 0.f, a6 = 0.f, a7 = 0.f;
    int e = 0;
    for (; e + 4 <= deg; e += 4) {
        int q0 = es[s0 + e + 0];
        int q1 = es[s0 + e + 1];
        int q2 = es[s0 + e + 2];
        int q3 = es[s0 + e + 3];
        uint2 u0 = xv[q0 * 16 + l4];
        uint2 u1 = xv[q1 * 16 + l4];
        uint2 u2 = xv[q2 * 16 + l4];
        uint2 u3 = xv[q3 * 16 + l4];
#pragma unroll
        for (int j = 0; j < 4; ++j) {
            unsigned lo = (j == 0) ? u0.x : (j == 1) ? u1.x : (j == 2) ? u2.x : u3.x;
            unsigned hi = (j == 0) ? u0.y : (j == 1) ? u1.y : (j == 2) ? u2.y : u3.y;
            f32x2 p0 = __builtin_amdgcn_cvt_pk_f32_fp8(lo, false);
            f32x2 p1 = __builtin_amdgcn_cvt_pk_f32_fp8(lo, true);
            f32x2 p2 = __builtin_amdgcn_cvt_pk_f32_fp8(hi, false);
            f32x2 p3 = __builtin_amdgcn_cvt_pk_f32_fp8(hi, true);
            a0 += p0.x; a1 += p0.y; a2 += p1.x; a3 += p1.y;
            a4 += p2.x; a5 += p2.y; a6 += p3.x; a7 += p3.y;
        }
    }
    for (; e < deg; ++e) {
        uint2 u = xv[es[s0 + e] * 16 + l4];
        f32x2 p0 = __builtin_amdgcn_cvt_pk_f32_fp8(u.x, false);
        f32x2 p1 = __builtin_amdgcn_cvt_pk_f32_fp8(u.x, true);
        f32x2 p2 = __builtin_amdgcn_cvt_pk_f32_fp8(u.y, false);
        f32x2 p3 = __builtin_amdgcn_cvt_pk_f32_fp8(u.y, true);
        a0 += p0.x; a1 += p0.y; a2 += p1.x; a3 += p1.y;
        a4 += p2.x; a5 += p2.y; a6 += p3.x; a7 += p3.y;
    }
    float inv = 1.0f / fmaxf((float)deg, 1.0f);
    uint4 o;
    o.x = (unsigned)f2bf(a0 * inv) | ((unsigned)f2bf(a1 * inv) << 16);
    o.y = (unsigned)f2bf(a2 * inv) | ((unsigned)f2bf(a3 * inv) << 16);
    o.z = (unsigned)f2bf(a4 * inv) | ((unsigned)f2bf(a5 * inv) << 16);
    o.w = (unsigned)f2bf(a6 * inv) | ((unsigned)f2bf(a7 * inv) << 16);
    *(uint4*)&meanb[node * 128 + 8 * l4] = o;
}

// ---------------------------------------------------------------------------
// Layer-2 gather (bf16 pl, zero LDS): half-wave (32 lanes) per node, lane
// owns 2 channels (uint = 2 bf16; 32 x 4B = 128B row). Grid 12500 x 256.
// Writes meanp fp32.
// ---------------------------------------------------------------------------
__global__ __launch_bounds__(256) void agg2g_kernel(const unsigned* __restrict__ es,
                                                    const int* __restrict__ rstart,
                                                    const int* __restrict__ rdeg,
                                                    const ushort* __restrict__ pb,
                                                    float* __restrict__ meanp) {
    int t = threadIdx.x;
    int node = blockIdx.x * 8 + (t >> 5);
    int l5 = t & 31;
    int s0 = rstart[node];
    int deg = rdeg[node];
    const unsigned* pbu = (const unsigned*)pb;  // row = 32 uint (64 bf16)
    float a0 = 0.f, a1 = 0.f;
    int e = 0;
    for (; e + 4 <= deg; e += 4) {
        unsigned u0 = pbu[es[s0 + e + 0] * 32 + l5];
        unsigned u1 = pbu[es[s0 + e + 1] * 32 + l5];
        unsigned u2 = pbu[es[s0 + e + 2] * 32 + l5];
        unsigned u3 = pbu[es[s0 + e + 3] * 32 + l5];
        a0 += bflo(u0) + bflo(u1) + bflo(u2) + bflo(u3);
        a1 += bfhi(u0) + bfhi(u1) + bfhi(u2) + bfhi(u3);
    }
    for (; e < deg; ++e) {
        unsigned u = pbu[es[s0 + e] * 32 + l5];
        a0 += bflo(u); a1 += bfhi(u);
    }
    float inv = 1.0f / fmaxf((float)deg, 1.0f);
    float2 o = {a0 * inv, a1 * inv};
    *(float2*)&meanp[node * 64 + 2 * l5] = o;
}

// ---------------------------------------------------------------------------
// GEMM1 (MFMA): h = relu(mean@W1l + x@W1r + b1); hb = bf16(h); pb = bf16(h@W2l).
// ---------------------------------------------------------------------------
__global__ __launch_bounds__(256) void gemm1_kernel(const ushort* __restrict__ meanb,
                                                    const ushort* __restrict__ xb,
                                                    const ushort* __restrict__ w1lp,
                                                    const ushort* __restrict__ w1rp,
                                                    const float* __restrict__ b1,
                                                    const ushort* __restrict__ w2lp,
                                                    ushort* __restrict__ hb,
                                                    ushort* __restrict__ pb) {
    __shared__ ushort As[64 * 136];
    int t = threadIdx.x;
    int node0 = blockIdx.x * 64;
    int w = t >> 6, l = t & 63;
    int lrow = w * 16 + (l & 15);
    int lkq = (l >> 4) * 8;
    int cq = l & 15, rq = (l >> 4) * 4;

    f32x4 acc[8];
#pragma unroll
    for (int i = 0; i < 8; ++i) acc[i] = (f32x4){0.f, 0.f, 0.f, 0.f};

    {
        const uint4* g = (const uint4*)(meanb + (size_t)node0 * 128);
#pragma unroll
        for (int i = 0; i < 4; ++i) {
            int chunk = t + 256 * i;
            *(uint4*)&As[(chunk >> 4) * 136 + (chunk & 15) * 8] = g[chunk];
        }
    }
    __syncthreads();
#pragma unroll
    for (int kt = 0; kt < 4; ++kt) {
        bf16x8 a = *(const bf16x8*)&As[lrow * 136 + kt * 32 + lkq];
        const bf16x8* bp = (const bf16x8*)w1lp + (kt * 8) * 64 + l;
#pragma unroll
        for (int nt = 0; nt < 8; ++nt)
            acc[nt] = __builtin_amdgcn_mfma_f32_16x16x32_bf16(a, bp[nt * 64], acc[nt], 0, 0, 0);
    }
    __syncthreads();

    {
        const uint4* g = (const uint4*)(xb + (size_t)node0 * 128);
#pragma unroll
        for (int i = 0; i < 4; ++i) {
            int chunk = t + 256 * i;
            *(uint4*)&As[(chunk >> 4) * 136 + (chunk & 15) * 8] = g[chunk];
        }
    }
    __syncthreads();
#pragma unroll
    for (int kt = 0; kt < 4; ++kt) {
        bf16x8 a = *(const bf16x8*)&As[lrow * 136 + kt * 32 + lkq];
        const bf16x8* bp = (const bf16x8*)w1rp + (kt * 8) * 64 + l;
#pragma unroll
        for (int nt = 0; nt < 8; ++nt)
            acc[nt] = __builtin_amdgcn_mfma_f32_16x16x32_bf16(a, bp[nt * 64], acc[nt], 0, 0, 0);
    }
    __syncthreads();

#pragma unroll
    for (int nt = 0; nt < 8; ++nt) {
        int n = nt * 16 + cq;
        float bias = b1[n];
#pragma unroll
        for (int r = 0; r < 4; ++r) {
            float hv = fmaxf(acc[nt][r] + bias, 0.0f);
            As[(w * 16 + rq + r) * 136 + n] = f2bf(hv);
        }
    }
    __syncthreads();

    {
        uint4* g = (uint4*)(hb + (size_t)node0 * 128);
#pragma unroll
        for (int i = 0; i < 4; ++i) {
            int chunk = t + 256 * i;
            if (node0 + (chunk >> 4) < NN)
                g[chunk] = *(const uint4*)&As[(chunk >> 4) * 136 + (chunk & 15) * 8];
        }
    }

    f32x4 acc2[4];
#pragma unroll
    for (int i = 0; i < 4; ++i) acc2[i] = (f32x4){0.f, 0.f, 0.f, 0.f};
#pragma unroll
    for (int kt = 0; kt < 4; ++kt) {
        bf16x8 a = *(const bf16x8*)&As[lrow * 136 + kt * 32 + lkq];
        const bf16x8* bp = (const bf16x8*)w2lp + (kt * 4) * 64 + l;
#pragma unroll
        for (int nt = 0; nt < 4; ++nt)
            acc2[nt] = __builtin_amdgcn_mfma_f32_16x16x32_bf16(a, bp[nt * 64], acc2[nt], 0, 0, 0);
    }
    __syncthreads();

#pragma unroll
    for (int nt = 0; nt < 4; ++nt)
#pragma unroll
        for (int r = 0; r < 4; ++r)
            As[(w * 16 + rq + r) * 136 + nt * 16 + cq] = f2bf(acc2[nt][r]);
    __syncthreads();
    {
        uint4* g = (uint4*)(pb + (size_t)node0 * 64);
#pragma unroll
        for (int i = 0; i < 2; ++i) {
            int chunk = t + 256 * i;
            if (node0 + (chunk >> 3) < NN)
                g[chunk] = *(const uint4*)&As[(chunk >> 3) * 136 + (chunk & 7) * 8];
        }
    }
}

// ---------------------------------------------------------------------------
// GEMM2 (MFMA): out = meanp + hb@W2r + b2.
// ---------------------------------------------------------------------------
__global__ __launch_bounds__(256) void gemm2_kernel(const float* __restrict__ meanp,
                                                    const ushort* __restrict__ hb,
                                                    const ushort* __restrict__ w2rp,
                                                    const float* __restrict__ b2,
                                                    float* __restrict__ out) {
    __shared__ ushort As[64 * 136];
    int t = threadIdx.x;
    int node0 = blockIdx.x * 64;
    int w = t >> 6, l = t & 63;
    int lrow = w * 16 + (l & 15);
    int lkq = (l >> 4) * 8;
    int cq = l & 15, rq = (l >> 4) * 4;

    {
        const uint4* g = (const uint4*)(hb + (size_t)node0 * 128);
#pragma unroll
        for (int i = 0; i < 4; ++i) {
            int chunk = t + 256 * i;
            *(uint4*)&As[(chunk >> 4) * 136 + (chunk & 15) * 8] = g[chunk];
        }
    }
    __syncthreads();

    f32x4 acc[4];
#pragma unroll
    for (int i = 0; i < 4; ++i) acc[i] = (f32x4){0.f, 0.f, 0.f, 0.f};
#pragma unroll
    for (int kt = 0; kt < 4; ++kt) {
        bf16x8 a = *(const bf16x8*)&As[lrow * 136 + kt * 32 + lkq];
        const bf16x8* bp = (const bf16x8*)w2rp + (kt * 4) * 64 + l;
#pragma unroll
        for (int nt = 0; nt < 4; ++nt)
            acc[nt] = __builtin_amdgcn_mfma_f32_16x16x32_bf16(a, bp[nt * 64], acc[nt], 0, 0, 0);
    }

#pragma unroll
    for (int nt = 0; nt < 4; ++nt) {
        int n = nt * 16 + cq;
        float bias = b2[n];
#pragma unroll
        for (int r = 0; r < 4; ++r) {
            int row = node0 + w * 16 + rq + r;
            if (row < NN)
                out[(size_t)row * 64 + n] = acc[nt][r] + bias + meanp[(size_t)row * 64 + n];
        }
    }
}

extern "C" void kernel_launch(void* const* d_in, const int* in_sizes, int n_in,
                              void* d_out, int out_size, void* d_ws, size_t ws_size,
                              hipStream_t stream) {
    const float* x   = (const float*)d_in[0];
    const int*   ei  = (const int*)d_in[1];
    const float* W1l = (const float*)d_in[2];
    const float* W1r = (const float*)d_in[3];
    const float* b1  = (const float*)d_in[4];
    const float* W2l = (const float*)d_in[5];
    const float* W2r = (const float*)d_in[6];
    const float* b2  = (const float*)d_in[7];

    const int* src = ei;
    const int* dst = ei + NE;

    int*      ws_i   = (int*)d_ws;
    int*      cc     = ws_i + OFF_CC;
    int*      rstart = ws_i + OFF_RST;
    int*      rdeg   = ws_i + OFF_RDG;
    unsigned* stage  = (unsigned*)(ws_i + OFF_STAGE);
    ushort*   xb     = (ushort*)(ws_i + OFF_XB);
    unsigned* xf8    = (unsigned*)(ws_i + OFF_XF8);
    ushort*   pb     = (ushort*)(ws_i + OFF_XF8);   // aliases xf8 (disjoint lifetime)
    ushort*   meanb  = (ushort*)(ws_i + OFF_MEANB);
    float*    meanp  = (float*)(ws_i + OFF_MEANB);  // aliases meanb (disjoint lifetime)
    ushort*   hb     = (ushort*)(ws_i + OFF_HB);
    ushort*   w1lp   = (ushort*)(ws_i + OFF_W1LP);
    ushort*   w1rp   = (ushort*)(ws_i + OFF_W1RP);
    ushort*   w2lp   = (ushort*)(ws_i + OFF_W2LP);
    ushort*   w2rp   = (ushort*)(ws_i + OFF_W2RP);

    // Prep: zero cursors, convert x (bf16+fp8), pack weights, partition, sort.
    hipMemsetAsync(cc, 0, 1024 * sizeof(int), stream);
    cvt_kernel<<<12500, 256, 0, stream>>>(x, xb, xf8);
    pack_kernel<<<24, 256, 0, stream>>>(W1l, W1r, W2l, W2r, w1lp, w1rp, w2lp, w2rp);
    cpart_kernel<<<PBLK, 1024, 0, stream>>>(src, dst, cc, stage);
    sort_kernel<<<KB, 256, 0, stream>>>(stage, cc, rstart, rdeg);

    // Layer 1
    agg1g_kernel<<<NN / 16, 256, 0, stream>>>(stage, rstart, rdeg, xf8, meanb);
    gemm1_kernel<<<(NN + 63) / 64, 256, 0, stream>>>(meanb, xb, w1lp, w1rp, b1, w2lp, hb, pb);

    // Layer 2 (aggregation commuted past W2l)
    agg2g_kernel<<<NN / 8, 256, 0, stream>>>(stage, rstart, rdeg, pb, meanp);
    gemm2_kernel<<<(NN + 63) / 64, 256, 0, stream>>>(meanp, hb, w2rp, b2, (float*)d_out);
}